// Round 1
// baseline (359.551 us; speedup 1.0000x reference)
//
#include <hip/hip_runtime.h>
#include <cstdint>
#include <cstddef>

typedef __bf16 bf16x8 __attribute__((ext_vector_type(8)));
typedef float f32x4 __attribute__((ext_vector_type(4)));
typedef unsigned short u16;

constexpr int S_LEN  = 2048;
constexpr int DMODEL = 2048;
constexpr int NHEAD  = 16;
constexpr int HDIM   = 128;
constexpr int WIN    = 512;

__device__ __forceinline__ u16 f2bf(float f) {
  union { float ff; uint32_t u; } a; a.ff = f;
  return (u16)((a.u + 0x7fffu + ((a.u >> 16) & 1u)) >> 16);  // RNE
}

// ---------------- fp32 -> bf16 convert ----------------
__global__ void cvt_kernel(const float* __restrict__ in, u16* __restrict__ out, int n4) {
  int i = blockIdx.x * blockDim.x + threadIdx.x;
  const int stride = gridDim.x * blockDim.x;
  for (; i < n4; i += stride) {
    float4 v = reinterpret_cast<const float4*>(in)[i];
    uint2 pk;
    pk.x = (uint32_t)f2bf(v.x) | ((uint32_t)f2bf(v.y) << 16);
    pk.y = (uint32_t)f2bf(v.z) | ((uint32_t)f2bf(v.w) << 16);
    reinterpret_cast<uint2*>(out)[i] = pk;
  }
}

// ---------------- rope tables (fp64 for accuracy, tiny) ----------------
__global__ void rope_kernel(float* __restrict__ rc, float* __restrict__ rs) {
  const int i = blockIdx.x * blockDim.x + threadIdx.x;  // s*64 + f
  const int s = i >> 6, f = i & 63;
  const double inv = exp(-(double)f * (log(10000.0) / 64.0));
  const double a = (double)s * inv;
  rc[i] = (float)cos(a);
  rs[i] = (float)sin(a);
}

// ---------------- 128x128 tile bf16 GEMM, C = A[M,K] * B[N,K]^T ----------------
// MODE: 0 = q (rope + scale, [B,H,S,Dh]) 1 = k (rope, [B,H,S,Dh])
//       2 = v (write transposed [B,H,Dh,S]) 3 = plain fp32 [M,N] store
template<int MODE>
__global__ __launch_bounds__(256, 2)
void gemm128(const u16* __restrict__ A, const u16* __restrict__ Bw,
             void* __restrict__ Cout,
             const float* __restrict__ rc, const float* __restrict__ rs) {
  constexpr int K = DMODEL;
  constexpr int BK = 64;
  __shared__ __align__(16) u16 As[128 * BK];
  __shared__ __align__(16) u16 Bs[128 * BK];
  const int tid = threadIdx.x;
  const int w = tid >> 6, lane = tid & 63;
  const int lr = lane & 15, lk = lane >> 4;
  const int wm = w >> 1, wn = w & 1;
  const int brow = blockIdx.y * 128;
  const int bcol = blockIdx.x * 128;

  f32x4 acc[4][4] = {};

  const int st_row = w * 32 + (lane >> 3);     // + i*8
  const int st_col = (lane & 7) * 8;
  const u16* Ag = A  + (size_t)(brow + st_row) * K + st_col;
  const u16* Bg = Bw + (size_t)(bcol + st_row) * K + st_col;
  u16* AsW = As + w * 32 * BK;
  u16* BsW = Bs + w * 32 * BK;

  for (int k0 = 0; k0 < K; k0 += BK) {
#pragma unroll
    for (int i = 0; i < 4; ++i)
      __builtin_amdgcn_global_load_lds(
          (const __attribute__((address_space(1))) void*)(Ag + (size_t)i * 8 * K + k0),
          (__attribute__((address_space(3))) void*)(AsW + i * 8 * BK), 16, 0, 0);
#pragma unroll
    for (int i = 0; i < 4; ++i)
      __builtin_amdgcn_global_load_lds(
          (const __attribute__((address_space(1))) void*)(Bg + (size_t)i * 8 * K + k0),
          (__attribute__((address_space(3))) void*)(BsW + i * 8 * BK), 16, 0, 0);
    __syncthreads();
#pragma unroll
    for (int kc = 0; kc < 2; ++kc) {
      bf16x8 a[4], b[4];
#pragma unroll
      for (int m = 0; m < 4; ++m)
        a[m] = *reinterpret_cast<const bf16x8*>(&As[(wm * 64 + m * 16 + lr) * BK + kc * 32 + lk * 8]);
#pragma unroll
      for (int n = 0; n < 4; ++n)
        b[n] = *reinterpret_cast<const bf16x8*>(&Bs[(wn * 64 + n * 16 + lr) * BK + kc * 32 + lk * 8]);
#pragma unroll
      for (int m = 0; m < 4; ++m)
#pragma unroll
        for (int n = 0; n < 4; ++n)
          acc[m][n] = __builtin_amdgcn_mfma_f32_16x16x32_bf16(a[m], b[n], acc[m][n], 0, 0, 0);
    }
    __syncthreads();
  }

  // ---- epilogue ----  C layout: col = lane&15, row = (lane>>4)*4 + reg (m89)
  if constexpr (MODE == 3) {
    float* O = reinterpret_cast<float*>(Cout);
#pragma unroll
    for (int m = 0; m < 4; ++m) {
      const int gm0 = brow + wm * 64 + m * 16 + lk * 4;
#pragma unroll
      for (int n = 0; n < 4; ++n) {
        const int gn = bcol + wn * 64 + n * 16 + lr;
#pragma unroll
        for (int j = 0; j < 4; ++j)
          O[(size_t)(gm0 + j) * DMODEL + gn] = acc[m][n][j];
      }
    }
  } else if constexpr (MODE == 2) {
    u16* V = reinterpret_cast<u16*>(Cout);
#pragma unroll
    for (int m = 0; m < 4; ++m) {
      const int gm0 = brow + wm * 64 + m * 16 + lk * 4;
      const int b = gm0 >> 11, s = gm0 & 2047;
#pragma unroll
      for (int n = 0; n < 4; ++n) {
        const int gn = bcol + wn * 64 + n * 16 + lr;
        const int h = gn >> 7, dh = gn & 127;
        uint2 pk;
        pk.x = (uint32_t)f2bf(acc[m][n][0]) | ((uint32_t)f2bf(acc[m][n][1]) << 16);
        pk.y = (uint32_t)f2bf(acc[m][n][2]) | ((uint32_t)f2bf(acc[m][n][3]) << 16);
        *reinterpret_cast<uint2*>(&V[((size_t)((b * NHEAD + h) * HDIM + dh)) * S_LEN + s]) = pk;
      }
    }
  } else {
    u16* QK = reinterpret_cast<u16*>(Cout);
#pragma unroll
    for (int m = 0; m < 4; ++m) {
      const int gm0 = brow + wm * 64 + m * 16 + lk * 4;
      const int b = gm0 >> 11, s0 = gm0 & 2047;
#pragma unroll
      for (int n = 0; n < 4; ++n) {
        const int gn = bcol + wn * 64 + n * 16 + lr;
        const int h = gn >> 7, dh = gn & 127;
        const int fi = dh >> 1;
        const bool ev = (dh & 1) == 0;
#pragma unroll
        for (int j = 0; j < 4; ++j) {
          float v = acc[m][n][j];
          float pp = __shfl_xor(v, 1, 64);        // partner channel (dh^1)
          const float c  = rc[(s0 + j) * 64 + fi];
          const float sn = rs[(s0 + j) * 64 + fi];
          float oo = ev ? (v * c - pp * sn) : (pp * sn + v * c);
          if constexpr (MODE == 0) oo *= 0.08838834764831845f;  // Dh^-0.5
          QK[((size_t)(b * NHEAD + h) * S_LEN + (s0 + j)) * HDIM + dh] = f2bf(oo);
        }
      }
    }
  }
}

// ---------------- sliding-window flash attention ----------------
// grid: (32 q-tiles, 32 b*h). block 256 = 4 waves, each wave: 16 q rows.
__global__ __launch_bounds__(256, 2)
void swa_kernel(const u16* __restrict__ Qp, const u16* __restrict__ Kp,
                const u16* __restrict__ Vt, u16* __restrict__ AO) {
  const int qt = blockIdx.x;
  const int bh = blockIdx.y;
  const int w = threadIdx.x >> 6, lane = threadIdx.x & 63;
  const int lr = lane & 15, lk = lane >> 4;
  const int qbase = qt * 64 + w * 16;
  const u16* Qb = Qp + (size_t)bh * S_LEN * HDIM;
  const u16* Kb = Kp + (size_t)bh * S_LEN * HDIM;
  const u16* Vb = Vt + (size_t)bh * HDIM * S_LEN;

  __shared__ __align__(16) u16 Ps[4 * 512];   // per-wave 16x32 P tile
  u16* Pw = Ps + w * 512;

  bf16x8 qf[4];
#pragma unroll
  for (int kc = 0; kc < 4; ++kc)
    qf[kc] = *reinterpret_cast<const bf16x8*>(&Qb[(size_t)(qbase + lr) * HDIM + kc * 32 + lk * 8]);

  f32x4 o[8] = {};
  float mrow[4] = {-1e30f, -1e30f, -1e30f, -1e30f};
  float lsum[4] = {0.f, 0.f, 0.f, 0.f};

  int kstart = qt * 64 - (WIN - 1);
  if (kstart < 0) kstart = 0;
  kstart &= ~31;
  const int kend = qt * 64 + 64;

  for (int kc0 = kstart; kc0 < kend; kc0 += 32) {
    // S = Q K^T (scale folded into q at projection)
    f32x4 sc[2] = {};
#pragma unroll
    for (int nf = 0; nf < 2; ++nf)
#pragma unroll
      for (int kc = 0; kc < 4; ++kc) {
        bf16x8 kf = *reinterpret_cast<const bf16x8*>(
            &Kb[(size_t)(kc0 + nf * 16 + lr) * HDIM + kc * 32 + lk * 8]);
        sc[nf] = __builtin_amdgcn_mfma_f32_16x16x32_bf16(qf[kc], kf, sc[nf], 0, 0, 0);
      }
    float p0v[4], p1v[4];
#pragma unroll
    for (int j = 0; j < 4; ++j) {
      const int qi = qbase + lk * 4 + j;
      const int k0j = kc0 + lr, k1j = kc0 + 16 + lr;
      const bool keep0 = (qi >= k0j) && (qi - k0j < WIN);
      const bool keep1 = (qi >= k1j) && (qi - k1j < WIN);
      float v0 = sc[0][j], v1 = sc[1][j];
      float mm = fmaxf(keep0 ? v0 : -1e30f, keep1 ? v1 : -1e30f);
      mm = fmaxf(mm, __shfl_xor(mm, 1, 64));
      mm = fmaxf(mm, __shfl_xor(mm, 2, 64));
      mm = fmaxf(mm, __shfl_xor(mm, 4, 64));
      mm = fmaxf(mm, __shfl_xor(mm, 8, 64));
      const float mnew  = fmaxf(mrow[j], mm);
      const float alpha = __expf(mrow[j] - mnew);   // finite sentinel: exp(0)=1 pre-first-key
      const float p0 = keep0 ? __expf(v0 - mnew) : 0.f;
      const float p1 = keep1 ? __expf(v1 - mnew) : 0.f;
      float cs = p0 + p1;
      cs += __shfl_xor(cs, 1, 64);
      cs += __shfl_xor(cs, 2, 64);
      cs += __shfl_xor(cs, 4, 64);
      cs += __shfl_xor(cs, 8, 64);
      lsum[j] = lsum[j] * alpha + cs;
      mrow[j] = mnew;
#pragma unroll
      for (int f = 0; f < 8; ++f) o[f][j] *= alpha;
      p0v[j] = p0; p1v[j] = p1;
    }
    // P -> per-wave LDS (C layout) then re-read in A-fragment layout
#pragma unroll
    for (int j = 0; j < 4; ++j) {
      Pw[(lk * 4 + j) * 32 + lr]      = f2bf(p0v[j]);
      Pw[(lk * 4 + j) * 32 + 16 + lr] = f2bf(p1v[j]);
    }
    bf16x8 pa = *reinterpret_cast<const bf16x8*>(&Pw[lr * 32 + lk * 8]);
#pragma unroll
    for (int f = 0; f < 8; ++f) {
      bf16x8 vf = *reinterpret_cast<const bf16x8*>(
          &Vb[(size_t)(f * 16 + lr) * S_LEN + kc0 + lk * 8]);   // V^T: contiguous keys
      o[f] = __builtin_amdgcn_mfma_f32_16x16x32_bf16(pa, vf, o[f], 0, 0, 0);
    }
  }

  const int b = bh >> 4, h = bh & 15;
  float inv[4];
#pragma unroll
  for (int j = 0; j < 4; ++j) inv[j] = 1.f / lsum[j];
#pragma unroll
  for (int f = 0; f < 8; ++f)
#pragma unroll
    for (int j = 0; j < 4; ++j) {
      const int qi = qbase + lk * 4 + j;
      AO[(size_t)(b * S_LEN + qi) * DMODEL + h * HDIM + f * 16 + lr] = f2bf(o[f][j] * inv[j]);
    }
}

extern "C" void kernel_launch(void* const* d_in, const int* in_sizes, int n_in,
                              void* d_out, int out_size, void* d_ws, size_t ws_size,
                              hipStream_t stream) {
  const float* x  = (const float*)d_in[0];
  const float* Wq = (const float*)d_in[1];
  const float* Wk = (const float*)d_in[2];
  const float* Wv = (const float*)d_in[3];
  const float* Wo = (const float*)d_in[4];
  float* out = (float*)d_out;

  // workspace layout (bf16 unless noted); total ~118.5 MB
  u16* p = (u16*)d_ws;
  u16* xb  = p; p += (size_t)4096 * 2048;
  u16* wqb = p; p += (size_t)2048 * 2048;
  u16* wkb = p; p += (size_t)2048 * 2048;
  u16* wvb = p; p += (size_t)2048 * 2048;
  u16* wob = p; p += (size_t)2048 * 2048;
  u16* qb  = p; p += (size_t)32 * 2048 * 128;   // [B,H,S,Dh]
  u16* kb  = p; p += (size_t)32 * 2048 * 128;   // [B,H,S,Dh]
  u16* vtb = p; p += (size_t)32 * 128 * 2048;   // [B,H,Dh,S]
  u16* aob = p; p += (size_t)4096 * 2048;       // [B*S, D]
  float* rc = (float*)p;
  float* rs = rc + (size_t)2048 * 64;

  cvt_kernel<<<2048, 256, 0, stream>>>(x,  xb,  4096 * 2048 / 4);
  cvt_kernel<<<1024, 256, 0, stream>>>(Wq, wqb, 2048 * 2048 / 4);
  cvt_kernel<<<1024, 256, 0, stream>>>(Wk, wkb, 2048 * 2048 / 4);
  cvt_kernel<<<1024, 256, 0, stream>>>(Wv, wvb, 2048 * 2048 / 4);
  cvt_kernel<<<1024, 256, 0, stream>>>(Wo, wob, 2048 * 2048 / 4);
  rope_kernel<<<512, 256, 0, stream>>>(rc, rs);

  dim3 gg(16, 32);  // N/128, M/128
  gemm128<0><<<gg, 256, 0, stream>>>(xb, wqb, qb, rc, rs);
  gemm128<1><<<gg, 256, 0, stream>>>(xb, wkb, kb, rc, rs);
  gemm128<2><<<gg, 256, 0, stream>>>(xb, wvb, vtb, nullptr, nullptr);
  swa_kernel<<<dim3(32, 32), 256, 0, stream>>>(qb, kb, vtb, aob);
  gemm128<3><<<gg, 256, 0, stream>>>(aob, wob, out, nullptr, nullptr);
}

// Round 2
// 297.203 us; speedup vs baseline: 1.2098x; 1.2098x over previous
//
#include <hip/hip_runtime.h>
#include <cstdint>
#include <cstddef>

typedef __bf16 bf16x8 __attribute__((ext_vector_type(8)));
typedef float f32x4 __attribute__((ext_vector_type(4)));
typedef float f32x16 __attribute__((ext_vector_type(16)));
typedef unsigned int u32x2v __attribute__((ext_vector_type(2)));
typedef unsigned short u16;

constexpr int S_LEN  = 2048;
constexpr int DMODEL = 2048;
constexpr int NHEAD  = 16;
constexpr int HDIM   = 128;
constexpr int WIN    = 512;

__device__ __forceinline__ u16 f2bf(float f) {
  union { float ff; uint32_t u; } a; a.ff = f;
  return (u16)((a.u + 0x7fffu + ((a.u >> 16) & 1u)) >> 16);  // RNE
}

__device__ __forceinline__ uint32_t cvtpk(float lo, float hi) {
  uint32_t r;
  asm("v_cvt_pk_bf16_f32 %0, %1, %2" : "=v"(r) : "v"(lo), "v"(hi));
  return r;
}

// ---------------- fp32 -> bf16 convert ----------------
__global__ void cvt_kernel(const float* __restrict__ in, u16* __restrict__ out, int n4) {
  int i = blockIdx.x * blockDim.x + threadIdx.x;
  const int stride = gridDim.x * blockDim.x;
  for (; i < n4; i += stride) {
    float4 v = reinterpret_cast<const float4*>(in)[i];
    uint2 pk;
    pk.x = (uint32_t)f2bf(v.x) | ((uint32_t)f2bf(v.y) << 16);
    pk.y = (uint32_t)f2bf(v.z) | ((uint32_t)f2bf(v.w) << 16);
    reinterpret_cast<uint2*>(out)[i] = pk;
  }
}

// ---------------- rope tables (fp64 for accuracy, tiny) ----------------
__global__ void rope_kernel(float* __restrict__ rc, float* __restrict__ rs) {
  const int i = blockIdx.x * blockDim.x + threadIdx.x;  // s*64 + f
  const int s = i >> 6, f = i & 63;
  const double inv = exp(-(double)f * (log(10000.0) / 64.0));
  const double a = (double)s * inv;
  rc[i] = (float)cos(a);
  rs[i] = (float)sin(a);
}

// ---------------- 128x128 tile bf16 GEMM, C = A[M,K] * B[N,K]^T ----------------
// MODE: 0 = q (rope + scale, [B,H,S,Dh]) 1 = k (rope, [B,H,S,Dh])
//       2 = v (write transposed [B,H,Dh,S]) 3 = plain fp32 [M,N] store
template<int MODE>
__global__ __launch_bounds__(256, 2)
void gemm128(const u16* __restrict__ A, const u16* __restrict__ Bw,
             void* __restrict__ Cout,
             const float* __restrict__ rc, const float* __restrict__ rs) {
  constexpr int K = DMODEL;
  constexpr int BK = 64;
  __shared__ __align__(16) u16 As[128 * BK];
  __shared__ __align__(16) u16 Bs[128 * BK];
  const int tid = threadIdx.x;
  const int w = tid >> 6, lane = tid & 63;
  const int lr = lane & 15, lk = lane >> 4;
  const int wm = w >> 1, wn = w & 1;
  const int brow = blockIdx.y * 128;
  const int bcol = blockIdx.x * 128;

  f32x4 acc[4][4] = {};

  const int st_row = w * 32 + (lane >> 3);     // + i*8
  const int st_col = (lane & 7) * 8;
  const u16* Ag = A  + (size_t)(brow + st_row) * K + st_col;
  const u16* Bg = Bw + (size_t)(bcol + st_row) * K + st_col;
  u16* AsW = As + w * 32 * BK;
  u16* BsW = Bs + w * 32 * BK;

  for (int k0 = 0; k0 < K; k0 += BK) {
#pragma unroll
    for (int i = 0; i < 4; ++i)
      __builtin_amdgcn_global_load_lds(
          (const __attribute__((address_space(1))) void*)(Ag + (size_t)i * 8 * K + k0),
          (__attribute__((address_space(3))) void*)(AsW + i * 8 * BK), 16, 0, 0);
#pragma unroll
    for (int i = 0; i < 4; ++i)
      __builtin_amdgcn_global_load_lds(
          (const __attribute__((address_space(1))) void*)(Bg + (size_t)i * 8 * K + k0),
          (__attribute__((address_space(3))) void*)(BsW + i * 8 * BK), 16, 0, 0);
    __syncthreads();
#pragma unroll
    for (int kc = 0; kc < 2; ++kc) {
      bf16x8 a[4], b[4];
#pragma unroll
      for (int m = 0; m < 4; ++m)
        a[m] = *reinterpret_cast<const bf16x8*>(&As[(wm * 64 + m * 16 + lr) * BK + kc * 32 + lk * 8]);
#pragma unroll
      for (int n = 0; n < 4; ++n)
        b[n] = *reinterpret_cast<const bf16x8*>(&Bs[(wn * 64 + n * 16 + lr) * BK + kc * 32 + lk * 8]);
#pragma unroll
      for (int m = 0; m < 4; ++m)
#pragma unroll
        for (int n = 0; n < 4; ++n)
          acc[m][n] = __builtin_amdgcn_mfma_f32_16x16x32_bf16(a[m], b[n], acc[m][n], 0, 0, 0);
    }
    __syncthreads();
  }

  // ---- epilogue ----  C layout: col = lane&15, row = (lane>>4)*4 + reg (m89)
  if constexpr (MODE == 3) {
    float* O = reinterpret_cast<float*>(Cout);
#pragma unroll
    for (int m = 0; m < 4; ++m) {
      const int gm0 = brow + wm * 64 + m * 16 + lk * 4;
#pragma unroll
      for (int n = 0; n < 4; ++n) {
        const int gn = bcol + wn * 64 + n * 16 + lr;
#pragma unroll
        for (int j = 0; j < 4; ++j)
          O[(size_t)(gm0 + j) * DMODEL + gn] = acc[m][n][j];
      }
    }
  } else if constexpr (MODE == 2) {
    u16* V = reinterpret_cast<u16*>(Cout);
#pragma unroll
    for (int m = 0; m < 4; ++m) {
      const int gm0 = brow + wm * 64 + m * 16 + lk * 4;
      const int b = gm0 >> 11, s = gm0 & 2047;
#pragma unroll
      for (int n = 0; n < 4; ++n) {
        const int gn = bcol + wn * 64 + n * 16 + lr;
        const int h = gn >> 7, dh = gn & 127;
        uint2 pk;
        pk.x = (uint32_t)f2bf(acc[m][n][0]) | ((uint32_t)f2bf(acc[m][n][1]) << 16);
        pk.y = (uint32_t)f2bf(acc[m][n][2]) | ((uint32_t)f2bf(acc[m][n][3]) << 16);
        *reinterpret_cast<uint2*>(&V[((size_t)((b * NHEAD + h) * HDIM + dh)) * S_LEN + s]) = pk;
      }
    }
  } else {
    u16* QK = reinterpret_cast<u16*>(Cout);
#pragma unroll
    for (int m = 0; m < 4; ++m) {
      const int gm0 = brow + wm * 64 + m * 16 + lk * 4;
      const int b = gm0 >> 11, s0 = gm0 & 2047;
#pragma unroll
      for (int n = 0; n < 4; ++n) {
        const int gn = bcol + wn * 64 + n * 16 + lr;
        const int h = gn >> 7, dh = gn & 127;
        const int fi = dh >> 1;
        const bool ev = (dh & 1) == 0;
#pragma unroll
        for (int j = 0; j < 4; ++j) {
          float v = acc[m][n][j];
          float pp = __shfl_xor(v, 1, 64);        // partner channel (dh^1)
          const float c  = rc[(s0 + j) * 64 + fi];
          const float sn = rs[(s0 + j) * 64 + fi];
          float oo = ev ? (v * c - pp * sn) : (pp * sn + v * c);
          if constexpr (MODE == 0) oo *= 0.08838834764831845f;  // Dh^-0.5
          QK[((size_t)(b * NHEAD + h) * S_LEN + (s0 + j)) * HDIM + dh] = f2bf(oo);
        }
      }
    }
  }
}

// ---------------- sliding-window flash attention, 32x32 MFMA, reg-only ----------------
// Each wave owns 32 q rows. Block = 4 waves = 128 q rows. Grid 16 x 32 (bh-swizzled).
// Swapped operands: P = mfma(K,Q) -> lane holds P[k][q=lane&31];
// O^T = mfma(Vt,Pt) -> lane holds O[d][q=lane&31]. Softmax state is lane-local.
__global__ __launch_bounds__(256, 2)
void swa2_kernel(const u16* __restrict__ Qp, const u16* __restrict__ Kp,
                 const u16* __restrict__ Vt, u16* __restrict__ AO) {
  // XCD swizzle: all 16 q-tiles of a bh on one XCD; 4 bh per XCD (~4MB K+V = L2)
  const int lin = blockIdx.x + gridDim.x * blockIdx.y;       // 0..511
  const int slot = lin >> 3;
  const int bh = (lin & 7) * 4 + (slot >> 4);
  const int qt = slot & 15;

  const int w = threadIdx.x >> 6;
  const int lane = threadIdx.x & 63;
  const int lq = lane & 31;          // q-col / k-row / d-row index
  const int hi = lane >> 5;
  const int qb = qt * 128 + w * 32;

  const u16* Qb = Qp + (size_t)bh * S_LEN * HDIM;
  const u16* Kb = Kp + (size_t)bh * S_LEN * HDIM;
  const u16* Vb = Vt + (size_t)bh * HDIM * S_LEN;

  // Q fragments (B-operand): qf[s] = Q[qb+lq][s*16 + hi*8 + j]
  bf16x8 qf[8];
#pragma unroll
  for (int s = 0; s < 8; ++s)
    qf[s] = *reinterpret_cast<const bf16x8*>(&Qb[(size_t)(qb + lq) * HDIM + s * 16 + hi * 8]);

  f32x16 ot[4] = {};                 // O^T accumulators: d = dt*32 + (r&3)+8*(r>>2)+4*hi
  float m = 0.f, lsum = 0.f;

  const int kstart = (qb >= WIN) ? qb - WIN : 0;   // qb-512, 32-aligned
  const int kend = qb + 32;

  for (int kc0 = kstart; kc0 < kend; kc0 += 32) {
    // issue all K and V loads up front
    bf16x8 kf[8];
#pragma unroll
    for (int s = 0; s < 8; ++s)
      kf[s] = *reinterpret_cast<const bf16x8*>(&Kb[(size_t)(kc0 + lq) * HDIM + s * 16 + hi * 8]);
    bf16x8 vfr[2][4];
#pragma unroll
    for (int ks = 0; ks < 2; ++ks)
#pragma unroll
      for (int dt = 0; dt < 4; ++dt)
        vfr[ks][dt] = *reinterpret_cast<const bf16x8*>(
            &Vb[(size_t)(dt * 32 + lq) * S_LEN + kc0 + ks * 16 + hi * 8]);

    // P[k][q]: col=lane&31=q, row k = (r&3)+8*(r>>2)+4*hi
    f32x16 P = {};
#pragma unroll
    for (int s = 0; s < 8; ++s)
      P = __builtin_amdgcn_mfma_f32_32x32x16_bf16(kf[s], qf[s], P, 0, 0, 0);

    const bool needmask = (kc0 + 32 > qb) || (qb + 31 - kc0 >= WIN);
    float p[16];
    float pmax = -1e30f;
#pragma unroll
    for (int r = 0; r < 16; ++r) {
      float v = P[r];
      if (needmask) {
        const int kk = kc0 + (r & 3) + ((r >> 2) << 3) + hi * 4;
        const int qq = qb + lq;
        const bool keep = (qq >= kk) && (qq - kk < WIN);
        v = keep ? v : -1e30f;
      }
      p[r] = v;
      pmax = fmaxf(pmax, v);
    }

    // T13 defer-max: rescale only if some row max exceeds m by >8
    if (__any(pmax - m > 8.f)) {
      const float rm = fmaxf(pmax, __shfl_xor(pmax, 32, 64));
      const float mnew = fmaxf(m, rm);
      const float alpha = __expf(m - mnew);
      lsum *= alpha;
#pragma unroll
      for (int dt = 0; dt < 4; ++dt)
#pragma unroll
        for (int r = 0; r < 16; ++r) ot[dt][r] *= alpha;
      m = mnew;
    }

    float ls = 0.f;
#pragma unroll
    for (int r = 0; r < 16; ++r) {
      p[r] = __expf(p[r] - m);       // exp(-1e30) underflows to 0 for masked
      ls += p[r];
    }
    lsum += ls;

    // T12: pack P to bf16 and redistribute halves for the PV B-fragment
    uint32_t W[8];
#pragma unroll
    for (int i = 0; i < 8; ++i) W[i] = cvtpk(p[2 * i], p[2 * i + 1]);
    u32x2v r02 = __builtin_amdgcn_permlane32_swap(W[0], W[2], false, false);
    u32x2v r13 = __builtin_amdgcn_permlane32_swap(W[1], W[3], false, false);
    u32x2v r46 = __builtin_amdgcn_permlane32_swap(W[4], W[6], false, false);
    u32x2v r57 = __builtin_amdgcn_permlane32_swap(W[5], W[7], false, false);

#pragma unroll
    for (int ks = 0; ks < 2; ++ks) {
      union { uint32_t u[4]; bf16x8 v; } pb;
      if (ks == 0) { pb.u[0] = r02[0]; pb.u[1] = r13[0]; pb.u[2] = r02[1]; pb.u[3] = r13[1]; }
      else         { pb.u[0] = r46[0]; pb.u[1] = r57[0]; pb.u[2] = r46[1]; pb.u[3] = r57[1]; }
#pragma unroll
      for (int dt = 0; dt < 4; ++dt)
        ot[dt] = __builtin_amdgcn_mfma_f32_32x32x16_bf16(vfr[ks][dt], pb.v, ot[dt], 0, 0, 0);
    }
  }

  const float lf = lsum + __shfl_xor(lsum, 32, 64);
  const float inv = 1.f / lf;
  const int b = bh >> 4, h = bh & 15;
  u16* Ob = AO + (size_t)(b * S_LEN + qb + lq) * DMODEL + h * HDIM;
#pragma unroll
  for (int dt = 0; dt < 4; ++dt)
#pragma unroll
    for (int rq = 0; rq < 4; ++rq) {
      uint2 pk;
      pk.x = cvtpk(ot[dt][rq * 4 + 0] * inv, ot[dt][rq * 4 + 1] * inv);
      pk.y = cvtpk(ot[dt][rq * 4 + 2] * inv, ot[dt][rq * 4 + 3] * inv);
      *reinterpret_cast<uint2*>(&Ob[dt * 32 + rq * 8 + hi * 4]) = pk;
    }
}

extern "C" void kernel_launch(void* const* d_in, const int* in_sizes, int n_in,
                              void* d_out, int out_size, void* d_ws, size_t ws_size,
                              hipStream_t stream) {
  const float* x  = (const float*)d_in[0];
  const float* Wq = (const float*)d_in[1];
  const float* Wk = (const float*)d_in[2];
  const float* Wv = (const float*)d_in[3];
  const float* Wo = (const float*)d_in[4];
  float* out = (float*)d_out;

  u16* p = (u16*)d_ws;
  u16* xb  = p; p += (size_t)4096 * 2048;
  u16* wqb = p; p += (size_t)2048 * 2048;
  u16* wkb = p; p += (size_t)2048 * 2048;
  u16* wvb = p; p += (size_t)2048 * 2048;
  u16* wob = p; p += (size_t)2048 * 2048;
  u16* qb  = p; p += (size_t)32 * 2048 * 128;   // [B,H,S,Dh]
  u16* kb  = p; p += (size_t)32 * 2048 * 128;   // [B,H,S,Dh]
  u16* vtb = p; p += (size_t)32 * 128 * 2048;   // [B,H,Dh,S]
  u16* aob = p; p += (size_t)4096 * 2048;       // [B*S, D]
  float* rc = (float*)p;
  float* rs = rc + (size_t)2048 * 64;

  cvt_kernel<<<2048, 256, 0, stream>>>(x,  xb,  4096 * 2048 / 4);
  cvt_kernel<<<1024, 256, 0, stream>>>(Wq, wqb, 2048 * 2048 / 4);
  cvt_kernel<<<1024, 256, 0, stream>>>(Wk, wkb, 2048 * 2048 / 4);
  cvt_kernel<<<1024, 256, 0, stream>>>(Wv, wvb, 2048 * 2048 / 4);
  cvt_kernel<<<1024, 256, 0, stream>>>(Wo, wob, 2048 * 2048 / 4);
  rope_kernel<<<512, 256, 0, stream>>>(rc, rs);

  dim3 gg(16, 32);  // N/128, M/128
  gemm128<0><<<gg, 256, 0, stream>>>(xb, wqb, qb, rc, rs);
  gemm128<1><<<gg, 256, 0, stream>>>(xb, wkb, kb, rc, rs);
  gemm128<2><<<gg, 256, 0, stream>>>(xb, wvb, vtb, nullptr, nullptr);
  swa2_kernel<<<dim3(16, 32), 256, 0, stream>>>(qb, kb, vtb, aob);
  gemm128<3><<<gg, 256, 0, stream>>>(aob, wob, out, nullptr, nullptr);
}

// Round 3
// 228.579 us; speedup vs baseline: 1.5730x; 1.3002x over previous
//
#include <hip/hip_runtime.h>
#include <cstdint>
#include <cstddef>

typedef __bf16 bf16x8 __attribute__((ext_vector_type(8)));
typedef float f32x4 __attribute__((ext_vector_type(4)));
typedef float f32x16 __attribute__((ext_vector_type(16)));
typedef unsigned int u32x2v __attribute__((ext_vector_type(2)));
typedef unsigned short u16;

constexpr int S_LEN  = 2048;
constexpr int DMODEL = 2048;
constexpr int NHEAD  = 16;
constexpr int HDIM   = 128;
constexpr int WIN    = 512;

__device__ __forceinline__ u16 f2bf(float f) {
  union { float ff; uint32_t u; } a; a.ff = f;
  return (u16)((a.u + 0x7fffu + ((a.u >> 16) & 1u)) >> 16);  // RNE
}

__device__ __forceinline__ uint32_t cvtpk(float lo, float hi) {
  uint32_t r;
  asm("v_cvt_pk_bf16_f32 %0, %1, %2" : "=v"(r) : "v"(lo), "v"(hi));
  return r;
}

// ---------------- fused fp32 -> bf16 convert (x, Wq, Wk, Wv, Wo) ----------------
__global__ void cvt_all(const float* __restrict__ x,  const float* __restrict__ wq,
                        const float* __restrict__ wk, const float* __restrict__ wv,
                        const float* __restrict__ wo,
                        u16* __restrict__ xb,  u16* __restrict__ wqb,
                        u16* __restrict__ wkb, u16* __restrict__ wvb,
                        u16* __restrict__ wob) {
  const int total = 6291456;  // float4 count: x 2M, each W 1M
  int i = blockIdx.x * blockDim.x + threadIdx.x;
  const int stride = gridDim.x * blockDim.x;
  for (; i < total; i += stride) {
    const int r = i >> 20;
    const float* src; u16* dst; int off;
    if (r < 2)       { src = x;  dst = xb;  off = i; }
    else if (r == 2) { src = wq; dst = wqb; off = i - (2 << 20); }
    else if (r == 3) { src = wk; dst = wkb; off = i - (3 << 20); }
    else if (r == 4) { src = wv; dst = wvb; off = i - (4 << 20); }
    else             { src = wo; dst = wob; off = i - (5 << 20); }
    float4 v = reinterpret_cast<const float4*>(src)[off];
    uint2 pk;
    pk.x = (uint32_t)f2bf(v.x) | ((uint32_t)f2bf(v.y) << 16);
    pk.y = (uint32_t)f2bf(v.z) | ((uint32_t)f2bf(v.w) << 16);
    reinterpret_cast<uint2*>(dst)[off] = pk;
  }
}

// ---------------- rope tables (fp64 for accuracy, tiny) ----------------
__global__ void rope_kernel(float* __restrict__ rc, float* __restrict__ rs) {
  const int i = blockIdx.x * blockDim.x + threadIdx.x;  // s*64 + f
  const int s = i >> 6, f = i & 63;
  const double inv = exp(-(double)f * (log(10000.0) / 64.0));
  const double a = (double)s * inv;
  rc[i] = (float)cos(a);
  rs[i] = (float)sin(a);
}

// ---------------- fused QKV GEMM: region = blockIdx.x>>4 (0 q, 1 k, 2 v) ----------------
__global__ __launch_bounds__(256, 2)
void gemm_qkv(const u16* __restrict__ A,
              const u16* __restrict__ wqb, const u16* __restrict__ wkb,
              const u16* __restrict__ wvb,
              u16* __restrict__ qout, u16* __restrict__ kout, u16* __restrict__ vtout,
              const float* __restrict__ rc, const float* __restrict__ rs) {
  constexpr int K = DMODEL;
  constexpr int BK = 64;
  __shared__ __align__(16) u16 As[128 * BK];
  __shared__ __align__(16) u16 Bs[128 * BK];
  const int region = blockIdx.x >> 4;
  const u16* Bw = region == 0 ? wqb : region == 1 ? wkb : wvb;
  const int tid = threadIdx.x;
  const int w = tid >> 6, lane = tid & 63;
  const int lr = lane & 15, lk = lane >> 4;
  const int wm = w >> 1, wn = w & 1;
  const int brow = blockIdx.y * 128;
  const int bcol = (blockIdx.x & 15) * 128;   // region-local column

  f32x4 acc[4][4] = {};

  const int st_row = w * 32 + (lane >> 3);
  const int st_col = (lane & 7) * 8;
  const u16* Ag = A  + (size_t)(brow + st_row) * K + st_col;
  const u16* Bg = Bw + (size_t)(bcol + st_row) * K + st_col;
  u16* AsW = As + w * 32 * BK;
  u16* BsW = Bs + w * 32 * BK;

  for (int k0 = 0; k0 < K; k0 += BK) {
#pragma unroll
    for (int i = 0; i < 4; ++i)
      __builtin_amdgcn_global_load_lds(
          (const __attribute__((address_space(1))) void*)(Ag + (size_t)i * 8 * K + k0),
          (__attribute__((address_space(3))) void*)(AsW + i * 8 * BK), 16, 0, 0);
#pragma unroll
    for (int i = 0; i < 4; ++i)
      __builtin_amdgcn_global_load_lds(
          (const __attribute__((address_space(1))) void*)(Bg + (size_t)i * 8 * K + k0),
          (__attribute__((address_space(3))) void*)(BsW + i * 8 * BK), 16, 0, 0);
    __syncthreads();
#pragma unroll
    for (int kc = 0; kc < 2; ++kc) {
      bf16x8 a[4], b[4];
#pragma unroll
      for (int m = 0; m < 4; ++m)
        a[m] = *reinterpret_cast<const bf16x8*>(&As[(wm * 64 + m * 16 + lr) * BK + kc * 32 + lk * 8]);
#pragma unroll
      for (int n = 0; n < 4; ++n)
        b[n] = *reinterpret_cast<const bf16x8*>(&Bs[(wn * 64 + n * 16 + lr) * BK + kc * 32 + lk * 8]);
#pragma unroll
      for (int m = 0; m < 4; ++m)
#pragma unroll
        for (int n = 0; n < 4; ++n)
          acc[m][n] = __builtin_amdgcn_mfma_f32_16x16x32_bf16(a[m], b[n], acc[m][n], 0, 0, 0);
    }
    __syncthreads();
  }

  if (region == 2) {            // V: write transposed [B,H,Dh,S] bf16
#pragma unroll
    for (int m = 0; m < 4; ++m) {
      const int gm0 = brow + wm * 64 + m * 16 + lk * 4;
      const int b = gm0 >> 11, s = gm0 & 2047;
#pragma unroll
      for (int n = 0; n < 4; ++n) {
        const int gn = bcol + wn * 64 + n * 16 + lr;
        const int h = gn >> 7, dh = gn & 127;
        uint2 pk;
        pk.x = (uint32_t)f2bf(acc[m][n][0]) | ((uint32_t)f2bf(acc[m][n][1]) << 16);
        pk.y = (uint32_t)f2bf(acc[m][n][2]) | ((uint32_t)f2bf(acc[m][n][3]) << 16);
        *reinterpret_cast<uint2*>(&vtout[((size_t)((b * NHEAD + h) * HDIM + dh)) * S_LEN + s]) = pk;
      }
    }
  } else {                      // Q/K: rope (+scale for Q), [B,H,S,Dh] bf16
    u16* QK = region == 0 ? qout : kout;
#pragma unroll
    for (int m = 0; m < 4; ++m) {
      const int gm0 = brow + wm * 64 + m * 16 + lk * 4;
      const int b = gm0 >> 11, s0 = gm0 & 2047;
#pragma unroll
      for (int n = 0; n < 4; ++n) {
        const int gn = bcol + wn * 64 + n * 16 + lr;
        const int h = gn >> 7, dh = gn & 127;
        const int fi = dh >> 1;
        const bool ev = (dh & 1) == 0;
#pragma unroll
        for (int j = 0; j < 4; ++j) {
          float v = acc[m][n][j];
          float pp = __shfl_xor(v, 1, 64);        // partner channel (dh^1)
          const float c  = rc[(s0 + j) * 64 + fi];
          const float sn = rs[(s0 + j) * 64 + fi];
          float oo = ev ? (v * c - pp * sn) : (pp * sn + v * c);
          if (region == 0) oo *= 0.08838834764831845f;   // Dh^-0.5
          QK[((size_t)(b * NHEAD + h) * S_LEN + (s0 + j)) * HDIM + dh] = f2bf(oo);
        }
      }
    }
  }
}

// ---------------- plain GEMM for the Wo projection (fp32 out) ----------------
__global__ __launch_bounds__(256, 2)
void gemm_o(const u16* __restrict__ A, const u16* __restrict__ Bw,
            float* __restrict__ O) {
  constexpr int K = DMODEL;
  constexpr int BK = 64;
  __shared__ __align__(16) u16 As[128 * BK];
  __shared__ __align__(16) u16 Bs[128 * BK];
  const int tid = threadIdx.x;
  const int w = tid >> 6, lane = tid & 63;
  const int lr = lane & 15, lk = lane >> 4;
  const int wm = w >> 1, wn = w & 1;
  const int brow = blockIdx.y * 128;
  const int bcol = blockIdx.x * 128;

  f32x4 acc[4][4] = {};

  const int st_row = w * 32 + (lane >> 3);
  const int st_col = (lane & 7) * 8;
  const u16* Ag = A  + (size_t)(brow + st_row) * K + st_col;
  const u16* Bg = Bw + (size_t)(bcol + st_row) * K + st_col;
  u16* AsW = As + w * 32 * BK;
  u16* BsW = Bs + w * 32 * BK;

  for (int k0 = 0; k0 < K; k0 += BK) {
#pragma unroll
    for (int i = 0; i < 4; ++i)
      __builtin_amdgcn_global_load_lds(
          (const __attribute__((address_space(1))) void*)(Ag + (size_t)i * 8 * K + k0),
          (__attribute__((address_space(3))) void*)(AsW + i * 8 * BK), 16, 0, 0);
#pragma unroll
    for (int i = 0; i < 4; ++i)
      __builtin_amdgcn_global_load_lds(
          (const __attribute__((address_space(1))) void*)(Bg + (size_t)i * 8 * K + k0),
          (__attribute__((address_space(3))) void*)(BsW + i * 8 * BK), 16, 0, 0);
    __syncthreads();
#pragma unroll
    for (int kc = 0; kc < 2; ++kc) {
      bf16x8 a[4], b[4];
#pragma unroll
      for (int m = 0; m < 4; ++m)
        a[m] = *reinterpret_cast<const bf16x8*>(&As[(wm * 64 + m * 16 + lr) * BK + kc * 32 + lk * 8]);
#pragma unroll
      for (int n = 0; n < 4; ++n)
        b[n] = *reinterpret_cast<const bf16x8*>(&Bs[(wn * 64 + n * 16 + lr) * BK + kc * 32 + lk * 8]);
#pragma unroll
      for (int m = 0; m < 4; ++m)
#pragma unroll
        for (int n = 0; n < 4; ++n)
          acc[m][n] = __builtin_amdgcn_mfma_f32_16x16x32_bf16(a[m], b[n], acc[m][n], 0, 0, 0);
    }
    __syncthreads();
  }

#pragma unroll
  for (int m = 0; m < 4; ++m) {
    const int gm0 = brow + wm * 64 + m * 16 + lk * 4;
#pragma unroll
    for (int n = 0; n < 4; ++n) {
      const int gn = bcol + wn * 64 + n * 16 + lr;
#pragma unroll
      for (int j = 0; j < 4; ++j)
        O[(size_t)(gm0 + j) * DMODEL + gn] = acc[m][n][j];
    }
  }
}

// ---------------- sliding-window flash attention, LDS-staged K/V ----------------
// Block = 4 waves x 32 q rows = 128 rows. K/V staged per 64-key chunk, double-buffered,
// XOR-swizzled (pre-swizzled global source + swizzled ds_read). Softmax in-register.
__global__ __launch_bounds__(256, 2)
void swa3_kernel(const u16* __restrict__ Qp, const u16* __restrict__ Kp,
                 const u16* __restrict__ Vt, u16* __restrict__ AO) {
  __shared__ __align__(16) u16 Ksh[2][64 * 128];    // [64 keys][128 dh], rows 256B, swizzled
  __shared__ __align__(16) u16 Vsh[2][128 * 64];    // [128 dh][64 keys], rows 128B, swizzled

  // XCD swizzle: 16 q-tiles of one bh contiguous; 4 bh per XCD (K+V 4MB = one L2)
  const int lin = blockIdx.x + gridDim.x * blockIdx.y;   // 0..511
  const int slot = lin >> 3;
  const int bh = (lin & 7) * 4 + (slot >> 4);
  const int qt = slot & 15;

  const int w = threadIdx.x >> 6;
  const int lane = threadIdx.x & 63;
  const int lq = lane & 31, hi = lane >> 5;
  const int qb_blk = qt * 128;
  const int qw = qb_blk + w * 32;                 // this wave's 32 q rows
  const int qq = qw + lq;

  const u16* Qb = Qp + (size_t)bh * S_LEN * HDIM;
  const u16* Kb = Kp + (size_t)bh * S_LEN * HDIM;
  const u16* Vb = Vt + (size_t)bh * HDIM * S_LEN;

  // Q fragments (B-operand): qf[s] = Q[qw+lq][s*16 + hi*8 + j]
  bf16x8 qf[8];
#pragma unroll
  for (int s = 0; s < 8; ++s)
    qf[s] = *reinterpret_cast<const bf16x8*>(&Qb[(size_t)qq * HDIM + s * 16 + hi * 8]);

  f32x16 ot[4] = {};          // O^T: d = dt*32 + (r&3)+8*(r>>2)+4*hi, q = lq
  float m = 0.f, lsum = 0.f;

  const int c_lo = (qb_blk >= WIN) ? qb_blk - WIN : 0;
  const int c_hi = qb_blk + 128;

  // stage 64-key chunk kc into buffer buf (pre-swizzled source, linear LDS dest)
  auto stage = [&](int buf, int kc) {
#pragma unroll
    for (int i = 0; i < 4; ++i) {       // K: 1024 16B-units, 16 units/row
      const int u = i * 256 + w * 64 + lane;
      const int row = u >> 4, sl = (u & 15) ^ (row & 7);
      __builtin_amdgcn_global_load_lds(
          (const __attribute__((address_space(1))) void*)(Kb + (size_t)(kc + row) * HDIM + sl * 8),
          (__attribute__((address_space(3))) void*)(&Ksh[buf][(size_t)(i * 256 + w * 64) * 8]),
          16, 0, 0);
    }
#pragma unroll
    for (int i = 0; i < 4; ++i) {       // V: 1024 16B-units, 8 units/row
      const int u = i * 256 + w * 64 + lane;
      const int row = u >> 3, sl = (u & 7) ^ (row & 7);
      __builtin_amdgcn_global_load_lds(
          (const __attribute__((address_space(1))) void*)(Vb + (size_t)row * S_LEN + kc + sl * 8),
          (__attribute__((address_space(3))) void*)(&Vsh[buf][(size_t)(i * 256 + w * 64) * 8]),
          16, 0, 0);
    }
  };

  int buf = 0;
  stage(0, c_lo);
  __syncthreads();

  for (int kc = c_lo; kc < c_hi; kc += 64, buf ^= 1) {
    if (kc + 64 < c_hi) stage(buf ^ 1, kc + 64);

#pragma unroll
    for (int half = 0; half < 2; ++half) {
      const int kch = kc + half * 32;
      if (kch > qw + 31 || kch < qw - 542) continue;   // wave-uniform skip

      // QK^T: P[k][q], k-row = (r&3)+8*(r>>2)+4*hi, q-col = lq
      f32x16 P = {};
#pragma unroll
      for (int s = 0; s < 8; ++s) {
        const int row = half * 32 + lq;
        const int byte = row * 256 + ((s * 32 + hi * 16) ^ ((row & 7) << 4));
        bf16x8 kf = *reinterpret_cast<const bf16x8*>(&Ksh[buf][byte >> 1]);
        P = __builtin_amdgcn_mfma_f32_32x32x16_bf16(kf, qf[s], P, 0, 0, 0);
      }

      const bool needmask = (kch + 32 > qw) || (qw + 31 - kch >= WIN);
      float p[16];
      float pmax = -1e30f;
#pragma unroll
      for (int r = 0; r < 16; ++r) {
        float v = P[r];
        if (needmask) {
          const int kk = kch + (r & 3) + ((r >> 2) << 3) + hi * 4;
          const bool keep = (qq >= kk) && (qq - kk < WIN);
          v = keep ? v : -1e30f;
        }
        p[r] = v;
        pmax = fmaxf(pmax, v);
      }

      // T13 defer-max
      if (__any(pmax - m > 8.f)) {
        const float rm = fmaxf(pmax, __shfl_xor(pmax, 32, 64));
        const float mnew = fmaxf(m, rm);
        const float alpha = __expf(m - mnew);
        lsum *= alpha;
#pragma unroll
        for (int dt = 0; dt < 4; ++dt)
#pragma unroll
          for (int r = 0; r < 16; ++r) ot[dt][r] *= alpha;
        m = mnew;
      }

      float ls = 0.f;
#pragma unroll
      for (int r = 0; r < 16; ++r) {
        p[r] = __expf(p[r] - m);
        ls += p[r];
      }
      lsum += ls;

      // T12: pack to bf16 + permlane redistribute into PV B-fragments
      uint32_t W[8];
#pragma unroll
      for (int i = 0; i < 8; ++i) W[i] = cvtpk(p[2 * i], p[2 * i + 1]);
      u32x2v r02 = __builtin_amdgcn_permlane32_swap(W[0], W[2], false, false);
      u32x2v r13 = __builtin_amdgcn_permlane32_swap(W[1], W[3], false, false);
      u32x2v r46 = __builtin_amdgcn_permlane32_swap(W[4], W[6], false, false);
      u32x2v r57 = __builtin_amdgcn_permlane32_swap(W[5], W[7], false, false);

#pragma unroll
      for (int ks = 0; ks < 2; ++ks) {
        union { uint32_t u[4]; bf16x8 v; } pb;
        if (ks == 0) { pb.u[0] = r02[0]; pb.u[1] = r13[0]; pb.u[2] = r02[1]; pb.u[3] = r13[1]; }
        else         { pb.u[0] = r46[0]; pb.u[1] = r57[0]; pb.u[2] = r46[1]; pb.u[3] = r57[1]; }
#pragma unroll
        for (int dt = 0; dt < 4; ++dt) {
          const int d = dt * 32 + lq;
          const int byte = d * 128 + ((half * 64 + ks * 32 + hi * 16) ^ ((d & 7) << 4));
          bf16x8 vf = *reinterpret_cast<const bf16x8*>(&Vsh[buf][byte >> 1]);
          ot[dt] = __builtin_amdgcn_mfma_f32_32x32x16_bf16(vf, pb.v, ot[dt], 0, 0, 0);
        }
      }
    }
    __syncthreads();   // staging of next chunk done + all waves done reading buf
  }

  const float lf = lsum + __shfl_xor(lsum, 32, 64);
  const float inv = 1.f / lf;
  const int b = bh >> 4, h = bh & 15;
  u16* Ob = AO + (size_t)(b * S_LEN + qq) * DMODEL + h * HDIM;
#pragma unroll
  for (int dt = 0; dt < 4; ++dt)
#pragma unroll
    for (int rq = 0; rq < 4; ++rq) {
      uint2 pk;
      pk.x = cvtpk(ot[dt][rq * 4 + 0] * inv, ot[dt][rq * 4 + 1] * inv);
      pk.y = cvtpk(ot[dt][rq * 4 + 2] * inv, ot[dt][rq * 4 + 3] * inv);
      *reinterpret_cast<uint2*>(&Ob[dt * 32 + rq * 8 + hi * 4]) = pk;
    }
}

extern "C" void kernel_launch(void* const* d_in, const int* in_sizes, int n_in,
                              void* d_out, int out_size, void* d_ws, size_t ws_size,
                              hipStream_t stream) {
  const float* x  = (const float*)d_in[0];
  const float* Wq = (const float*)d_in[1];
  const float* Wk = (const float*)d_in[2];
  const float* Wv = (const float*)d_in[3];
  const float* Wo = (const float*)d_in[4];
  float* out = (float*)d_out;

  u16* p = (u16*)d_ws;
  u16* xb  = p; p += (size_t)4096 * 2048;
  u16* wqb = p; p += (size_t)2048 * 2048;
  u16* wkb = p; p += (size_t)2048 * 2048;
  u16* wvb = p; p += (size_t)2048 * 2048;
  u16* wob = p; p += (size_t)2048 * 2048;
  u16* qb  = p; p += (size_t)32 * 2048 * 128;   // [B,H,S,Dh]
  u16* kb  = p; p += (size_t)32 * 2048 * 128;   // [B,H,S,Dh]
  u16* vtb = p; p += (size_t)32 * 128 * 2048;   // [B,H,Dh,S]
  u16* aob = p; p += (size_t)4096 * 2048;       // [B*S, D]
  float* rc = (float*)p;
  float* rs = rc + (size_t)2048 * 64;

  cvt_all<<<3072, 256, 0, stream>>>(x, Wq, Wk, Wv, Wo, xb, wqb, wkb, wvb, wob);
  rope_kernel<<<512, 256, 0, stream>>>(rc, rs);
  gemm_qkv<<<dim3(48, 32), 256, 0, stream>>>(xb, wqb, wkb, wvb, qb, kb, vtb, rc, rs);
  swa3_kernel<<<dim3(16, 32), 256, 0, stream>>>(qb, kb, vtb, aob);
  gemm_o<<<dim3(16, 32), 256, 0, stream>>>(aob, wob, out);
}